// Round 10
// baseline (309.082 us; speedup 1.0000x reference)
//
#include <hip/hip_runtime.h>

typedef short bf16x8 __attribute__((ext_vector_type(8)));
typedef float f32x4 __attribute__((ext_vector_type(4)));
typedef unsigned int u32x2 __attribute__((ext_vector_type(2)));
typedef unsigned int u32x4 __attribute__((ext_vector_type(4)));

#define AS1 __attribute__((address_space(1)))
#define AS3 __attribute__((address_space(3)))

__device__ __forceinline__ void gld16(void* lds, const void* g) {
  __builtin_amdgcn_global_load_lds((const AS1 unsigned int*)g,
                                   (AS3 unsigned int*)lds, 16, 0, 0);
}

__device__ __forceinline__ unsigned short f2bf(float f) {
  union { float f; unsigned int u; } c; c.f = f;
  return (unsigned short)((c.u + 0x7FFFu + ((c.u >> 16) & 1u)) >> 16);
}

// single-instruction RNE f32->bf16
__device__ __forceinline__ unsigned short cvt1(float x) {
  unsigned int r;
  asm("v_cvt_pk_bf16_f32 %0, %1, %1" : "=v"(r) : "v"(x));
  return (unsigned short)r;
}

// packed RNE f32x2 -> bf16x2 in one instr
__device__ __forceinline__ unsigned int cvtpk(float lo, float hi) {
  unsigned int r;
  asm("v_cvt_pk_bf16_f32 %0, %1, %2" : "=v"(r) : "v"(lo), "v"(hi));
  return r;
}

__device__ __forceinline__ float bf2f(unsigned short u) {
  union { unsigned int u; float f; } c; c.u = ((unsigned int)u) << 16;
  return c.f;
}

// all four 1024x1024 weights in one dispatch (blockIdx.y selects)
__global__ void cvtw_kernel(const float4* w0, const float4* w1,
                            const float4* w2, const float4* w3,
                            ushort4* o0, ushort4* o1, ushort4* o2, ushort4* o3,
                            int n4) {
  const float4* in; ushort4* out;
  switch (blockIdx.y) {
    case 0: in = w0; out = o0; break;
    case 1: in = w1; out = o1; break;
    case 2: in = w2; out = o2; break;
    default: in = w3; out = o3; break;
  }
  int i = blockIdx.x * blockDim.x + threadIdx.x;
  int stride = gridDim.x * blockDim.x;
  for (; i < n4; i += stride) {
    float4 v = in[i];
    ushort4 o;
    o.x = f2bf(v.x); o.y = f2bf(v.y); o.z = f2bf(v.z); o.w = f2bf(v.w);
    out[i] = o;
  }
}

// ---------------- fused QKV projection GEMM (fp32 A in, cvt fused) ---------
// 128x128 tile, BK=32, 256 threads (4 waves, 2x2). 1D grid 1536, XCD-swizzled.
// A (x or enc) is read fp32 and converted in the reg-staging path; B (weights)
// staged via global_load_lds from the pre-converted bf16 copies.
__global__ __launch_bounds__(256) void gemm_qkv_kernel(
    const float* __restrict__ X,
    const float* __restrict__ E,
    const unsigned short* __restrict__ Wqb,
    const unsigned short* __restrict__ Wkb,
    const unsigned short* __restrict__ Wvb,
    const float* __restrict__ bq,
    const float* __restrict__ bk,
    const float* __restrict__ bv,
    unsigned short* __restrict__ Qw,
    unsigned short* __restrict__ Kw,
    unsigned short* __restrict__ VTw,
    float qscale)
{
  __shared__ alignas(16) unsigned short As[2][4 * 128 * 8];
  __shared__ alignas(16) unsigned short Bs[2][4 * 128 * 8];

  // bijective XCD swizzle: 1536 blocks, 192 per XCD
  const int bid = blockIdx.x;
  const int o = (bid & 7) * 192 + (bid >> 3);
  const int xx = o % 24;
  const int yy = o / 24;
  const int sec = xx >> 3;
  const int nx = xx & 7;

  const float* A = (sec == 0) ? X : E;
  const unsigned short* W = (sec == 0) ? Wqb : (sec == 1) ? Wkb : Wvb;
  const float* bias = (sec == 0) ? bq : (sec == 1) ? bk : bv;

  const int K = 1024, N = 1024;
  const int tid = threadIdx.x;
  const int lane = tid & 63;
  const int w = tid >> 6;
  const int wr = (w >> 1) * 64;
  const int wc = (w & 1) * 64;
  const int lrow = lane & 15;
  const int lk = lane >> 4;
  const long m0 = (long)yy * 128;
  const long n0 = (long)nx * 128;

  f32x4 acc[4][4] = {};

  const int c0 = tid, c1 = tid + 256;
  const float* Arow0 = A + (m0 + (c0 & 127)) * (long)K + (c0 >> 7) * 8;
  const float* Arow1 = A + (m0 + (c1 & 127)) * (long)K + (c1 >> 7) * 8;
  const unsigned short* Wg0 = W + (n0 + (c0 & 127)) * (long)K + (c0 >> 7) * 8;
  const unsigned short* Wg1 = W + (n0 + (c1 & 127)) * (long)K + (c1 >> 7) * 8;

  const int arow = wr + lrow;
  const int brow = wc + lrow;
  const int nt = K >> 5;

  // prologue: tile 0
  {
    float4 a00 = *(const float4*)(Arow0);
    float4 a01 = *(const float4*)(Arow0 + 4);
    float4 a10 = *(const float4*)(Arow1);
    float4 a11 = *(const float4*)(Arow1 + 4);
    gld16(Bs[0] + c0 * 8, Wg0);
    gld16(Bs[0] + c1 * 8, Wg1);
    u32x4 w0 = { cvtpk(a00.x, a00.y), cvtpk(a00.z, a00.w),
                 cvtpk(a01.x, a01.y), cvtpk(a01.z, a01.w) };
    *(u32x4*)(As[0] + c0 * 8) = w0;
    u32x4 w1 = { cvtpk(a10.x, a10.y), cvtpk(a10.z, a10.w),
                 cvtpk(a11.x, a11.y), cvtpk(a11.z, a11.w) };
    *(u32x4*)(As[0] + c1 * 8) = w1;
  }

  int cur = 0;
  for (int t = 0; t < nt; ++t) {
    __syncthreads();   // As/Bs[cur] ready (ds_write + gld16 drained)
    float4 a00, a01, a10, a11;
    const bool more = (t + 1 < nt);
    if (more) {
      const int kt = (t + 1) * 32;
      a00 = *(const float4*)(Arow0 + kt);
      a01 = *(const float4*)(Arow0 + kt + 4);
      a10 = *(const float4*)(Arow1 + kt);
      a11 = *(const float4*)(Arow1 + kt + 4);
      gld16(Bs[cur ^ 1] + c0 * 8, Wg0 + kt);
      gld16(Bs[cur ^ 1] + c1 * 8, Wg1 + kt);
    }
    const unsigned short* as = As[cur];
    const unsigned short* bs = Bs[cur];
    bf16x8 af[4], bfr[4];
#pragma unroll
    for (int i = 0; i < 4; ++i)
      af[i] = *(const bf16x8*)(as + (lk * 128 + arow + i * 16) * 8);
#pragma unroll
    for (int j = 0; j < 4; ++j)
      bfr[j] = *(const bf16x8*)(bs + (lk * 128 + brow + j * 16) * 8);
    if (sec != 2) {
#pragma unroll
      for (int i = 0; i < 4; ++i)
#pragma unroll
        for (int j = 0; j < 4; ++j)
          acc[i][j] = __builtin_amdgcn_mfma_f32_16x16x32_bf16(af[i], bfr[j], acc[i][j], 0, 0, 0);
    } else {
      // swapped: C[row = W-feature][col = t]
#pragma unroll
      for (int i = 0; i < 4; ++i)
#pragma unroll
        for (int j = 0; j < 4; ++j)
          acc[i][j] = __builtin_amdgcn_mfma_f32_16x16x32_bf16(bfr[i], af[j], acc[i][j], 0, 0, 0);
    }
    if (more) {
      u32x4 w0 = { cvtpk(a00.x, a00.y), cvtpk(a00.z, a00.w),
                   cvtpk(a01.x, a01.y), cvtpk(a01.z, a01.w) };
      *(u32x4*)(As[cur ^ 1] + c0 * 8) = w0;
      u32x4 w1 = { cvtpk(a10.x, a10.y), cvtpk(a10.z, a10.w),
                   cvtpk(a11.x, a11.y), cvtpk(a11.z, a11.w) };
      *(u32x4*)(As[cur ^ 1] + c1 * 8) = w1;
    }
    cur ^= 1;
  }

  if (sec != 2) {
    unsigned short* out = (sec == 0) ? Qw : Kw;
    const float scale = (sec == 0) ? qscale : 1.0f;
#pragma unroll
    for (int j = 0; j < 4; ++j) {
      const long col = n0 + wc + j * 16 + lrow;
      const float bv_ = bias[col];
#pragma unroll
      for (int i = 0; i < 4; ++i)
#pragma unroll
        for (int r = 0; r < 4; ++r) {
          const long row = m0 + wr + i * 16 + lk * 4 + r;
          out[row * (long)N + col] = cvt1((acc[i][j][r] + bv_) * scale);
        }
    }
  } else {
    // V^T: feat = n0 + wc + i*16 + lk*4 + r, t = m0 + wr + j*16 + lrow
#pragma unroll
    for (int i = 0; i < 4; ++i)
#pragma unroll
      for (int r = 0; r < 4; ++r) {
        const long feat = n0 + wc + i * 16 + lk * 4 + r;
        const float bv_ = bias[feat];
#pragma unroll
        for (int j = 0; j < 4; ++j) {
          const long col = m0 + wr + j * 16 + lrow;
          VTw[feat * 8192 + col] = cvt1(acc[i][j][r] + bv_);
        }
      }
  }
}

// ---------------- final projection GEMM (128x128, f32 out, XCD-swizzled) ---
__global__ __launch_bounds__(256) void gemm_p_kernel(
    const unsigned short* __restrict__ A,
    const unsigned short* __restrict__ W,
    const float* __restrict__ bias,
    float* __restrict__ outF)
{
  __shared__ alignas(16) unsigned short As[2][4 * 128 * 8];
  __shared__ alignas(16) unsigned short Bs[2][4 * 128 * 8];

  const int bid = blockIdx.x;
  const int o = (bid & 7) * 64 + (bid >> 3);
  const int nx = o & 7;
  const int yy = o >> 3;

  const int K = 1024, N = 1024;
  const int tid = threadIdx.x;
  const int lane = tid & 63;
  const int w = tid >> 6;
  const int wr = (w >> 1) * 64;
  const int wc = (w & 1) * 64;
  const int lrow = lane & 15;
  const int lk = lane >> 4;
  const long m0 = (long)yy * 128;
  const long n0 = (long)nx * 128;

  f32x4 acc[4][4] = {};

  const int c0 = tid, c1 = tid + 256;
  const unsigned short* Ag0 = A + (m0 + (c0 & 127)) * (long)K + (c0 >> 7) * 8;
  const unsigned short* Ag1 = A + (m0 + (c1 & 127)) * (long)K + (c1 >> 7) * 8;
  const unsigned short* Wg0 = W + (n0 + (c0 & 127)) * (long)K + (c0 >> 7) * 8;
  const unsigned short* Wg1 = W + (n0 + (c1 & 127)) * (long)K + (c1 >> 7) * 8;

  const int arow = wr + lrow;
  const int brow = wc + lrow;
  const int nt = K >> 5;

  gld16(As[0] + c0 * 8, Ag0);
  gld16(As[0] + c1 * 8, Ag1);
  gld16(Bs[0] + c0 * 8, Wg0);
  gld16(Bs[0] + c1 * 8, Wg1);

  int cur = 0;
  for (int t = 0; t < nt; ++t) {
    __syncthreads();
    if (t + 1 < nt) {
      const int kt = (t + 1) * 32;
      gld16(As[cur ^ 1] + c0 * 8, Ag0 + kt);
      gld16(As[cur ^ 1] + c1 * 8, Ag1 + kt);
      gld16(Bs[cur ^ 1] + c0 * 8, Wg0 + kt);
      gld16(Bs[cur ^ 1] + c1 * 8, Wg1 + kt);
    }
    const unsigned short* as = As[cur];
    const unsigned short* bs = Bs[cur];
    bf16x8 af[4], bfr[4];
#pragma unroll
    for (int i = 0; i < 4; ++i)
      af[i] = *(const bf16x8*)(as + (lk * 128 + arow + i * 16) * 8);
#pragma unroll
    for (int j = 0; j < 4; ++j)
      bfr[j] = *(const bf16x8*)(bs + (lk * 128 + brow + j * 16) * 8);
#pragma unroll
    for (int i = 0; i < 4; ++i)
#pragma unroll
      for (int j = 0; j < 4; ++j)
        acc[i][j] = __builtin_amdgcn_mfma_f32_16x16x32_bf16(af[i], bfr[j], acc[i][j], 0, 0, 0);
    cur ^= 1;
  }

#pragma unroll
  for (int j = 0; j < 4; ++j) {
    const long col = n0 + wc + j * 16 + lrow;
    const float bv_ = bias[col];
#pragma unroll
    for (int i = 0; i < 4; ++i)
#pragma unroll
      for (int r = 0; r < 4; ++r) {
        const long row = m0 + wr + i * 16 + lk * 4 + r;
        outF[row * (long)N + col] = acc[i][j][r] + bv_;
      }
  }
}

// ---------------- Flash attention (split-K, QBLK=128, V^T input) -----------
// EXACT R7 inner loop; each block handles half the K range (16 tiles).
// Epilogue writes unnormalized O (bf16) + (l, m) (f32); combine kernel merges.
__global__ __launch_bounds__(256) void attn_kernel(
    const unsigned short* __restrict__ Q,
    const unsigned short* __restrict__ K,
    const unsigned short* __restrict__ VT,
    unsigned short* __restrict__ Op,   // [sp][bh][ql][64] bf16 (unnormalized)
    float2* __restrict__ Lm)           // [sp][bh][ql] (l, m)
{
  __shared__ alignas(16) unsigned short Ks[2][8 * 64 * 8];  // [buf][dblk][t][8] linear
  __shared__ alignas(16) unsigned short Vt[2][64 * 64];     // [buf][d][t] chunk-swizzled
  __shared__ alignas(16) unsigned short Ps[128 * 72];       // [q][t] stride-72, wave-private rows

  const int tid = threadIdx.x;
  const int lane = tid & 63;
  const int w = tid >> 6;
  const int lrow = lane & 15;
  const int lk = lane >> 4;

  // XCD-aware decode: 2048 blocks; id = r8 + 8*(qt + 16*(sp + 2*s))
  const int id = blockIdx.x;
  const int r8 = id & 7;
  const int qt = (id >> 3) & 15;
  const int sp = (id >> 7) & 1;
  const int s = id >> 8;
  const int bh = r8 + 8 * s;
  const int h = bh & 15, b = bh >> 4;
  const long C = 1024, T = 2048, NQ = 2048;
  const int kt0 = sp * 1024;
  const int ktEnd = kt0 + 1024;

  const unsigned short* Qg = Q + ((long)b * NQ + qt * 128) * C + h * 64;
  const unsigned short* Kg0 = K + (long)b * T * C + h * 64;
  const unsigned short* Vg0 = VT + (long)(h * 64) * 8192 + b * 2048;

  {
    int c = tid;
    gld16(Ks[0] + c * 8, Kg0 + (long)(kt0 + (c & 63)) * C + (c >> 6) * 8);
    c = tid + 256;
    gld16(Ks[0] + c * 8, Kg0 + (long)(kt0 + (c & 63)) * C + (c >> 6) * 8);
    c = tid;
    gld16(Vt[0] + c * 8, Vg0 + (long)(c >> 3) * 8192 + kt0 + (((c & 7) ^ ((c >> 3) & 7)) * 8));
    c = tid + 256;
    gld16(Vt[0] + c * 8, Vg0 + (long)(c >> 3) * 8192 + kt0 + (((c & 7) ^ ((c >> 3) & 7)) * 8));
  }
  bf16x8 qf[2][2];
#pragma unroll
  for (int f = 0; f < 2; ++f)
#pragma unroll
    for (int kk = 0; kk < 2; ++kk)
      qf[f][kk] = *(const bf16x8*)(Qg + (long)(f * 64 + w * 16 + lrow) * C + (kk * 4 + lk) * 8);

  bf16x8 ones;
#pragma unroll
  for (int e = 0; e < 8; ++e) ones[e] = (short)0x3F80;

  __syncthreads();

  f32x4 oA[4] = {}, oB[4] = {};
  f32x4 olA = {}, olB = {};
  float mrA = 0.f, mrB = 0.f;
  int cur = 0;

  const int qrow0 = w * 16 + lrow;

  for (int kt = kt0; kt < ktEnd; kt += 64) {
    const bool more = (kt + 64 < ktEnd);
    if (more) {
      int c = tid;
      gld16(Ks[cur ^ 1] + c * 8, Kg0 + (long)(kt + 64 + (c & 63)) * C + (c >> 6) * 8);
      gld16(Vt[cur ^ 1] + c * 8,
            Vg0 + (long)(c >> 3) * 8192 + kt + 64 + (((c & 7) ^ ((c >> 3) & 7)) * 8));
      c = tid + 256;
      gld16(Ks[cur ^ 1] + c * 8, Kg0 + (long)(kt + 64 + (c & 63)) * C + (c >> 6) * 8);
      gld16(Vt[cur ^ 1] + c * 8,
            Vg0 + (long)(c >> 3) * 8192 + kt + 64 + (((c & 7) ^ ((c >> 3) & 7)) * 8));
    }

    // ---- S^T = K Q^T, preseeded with -mr ----
    f32x4 sA[4], sB[4];
#pragma unroll
    for (int j = 0; j < 4; ++j)
#pragma unroll
      for (int r = 0; r < 4; ++r) { sA[j][r] = -mrA; sB[j][r] = -mrB; }

    __builtin_amdgcn_s_setprio(1);
#pragma unroll
    for (int kk = 0; kk < 2; ++kk) {
#pragma unroll
      for (int j = 0; j < 4; ++j) {
        bf16x8 kf = *(const bf16x8*)(Ks[cur] + ((kk * 4 + lk) * 64 + j * 16 + lrow) * 8);
        sA[j] = __builtin_amdgcn_mfma_f32_16x16x32_bf16(kf, qf[0][kk], sA[j], 0, 0, 0);
        sB[j] = __builtin_amdgcn_mfma_f32_16x16x32_bf16(kf, qf[1][kk], sB[j], 0, 0, 0);
      }
    }
    __builtin_amdgcn_s_setprio(0);

    // ---- lane-local online softmax; s is already S - mr ----
    float pmA, pmB;
    {
      float a = fmaxf(fmaxf(fmaxf(sA[0][0], sA[0][1]), fmaxf(sA[0][2], sA[0][3])),
                      fmaxf(fmaxf(sA[1][0], sA[1][1]), fmaxf(sA[1][2], sA[1][3])));
      float b2 = fmaxf(fmaxf(fmaxf(sA[2][0], sA[2][1]), fmaxf(sA[2][2], sA[2][3])),
                       fmaxf(fmaxf(sA[3][0], sA[3][1]), fmaxf(sA[3][2], sA[3][3])));
      pmA = fmaxf(a, b2);
      pmA = fmaxf(pmA, __shfl_xor(pmA, 16));
      pmA = fmaxf(pmA, __shfl_xor(pmA, 32));
      float c2 = fmaxf(fmaxf(fmaxf(sB[0][0], sB[0][1]), fmaxf(sB[0][2], sB[0][3])),
                       fmaxf(fmaxf(sB[1][0], sB[1][1]), fmaxf(sB[1][2], sB[1][3])));
      float d2 = fmaxf(fmaxf(fmaxf(sB[2][0], sB[2][1]), fmaxf(sB[2][2], sB[2][3])),
                       fmaxf(fmaxf(sB[3][0], sB[3][1]), fmaxf(sB[3][2], sB[3][3])));
      pmB = fmaxf(c2, d2);
      pmB = fmaxf(pmB, __shfl_xor(pmB, 16));
      pmB = fmaxf(pmB, __shfl_xor(pmB, 32));
    }
    if (__any(fmaxf(pmA, pmB) > 8.0f)) {
      const float dmA = fmaxf(pmA, 0.f);
      const float alA = __builtin_amdgcn_exp2f(-dmA);
      mrA += dmA; olA *= alA;
      const float dmB = fmaxf(pmB, 0.f);
      const float alB = __builtin_amdgcn_exp2f(-dmB);
      mrB += dmB; olB *= alB;
#pragma unroll
      for (int j = 0; j < 4; ++j) {
        oA[j] *= alA;
        oB[j] *= alB;
#pragma unroll
        for (int r = 0; r < 4; ++r) { sA[j][r] -= dmA; sB[j][r] -= dmB; }
      }
    }
#pragma unroll
    for (int j = 0; j < 4; ++j) {
      float p0 = __builtin_amdgcn_exp2f(sA[j][0]);
      float p1 = __builtin_amdgcn_exp2f(sA[j][1]);
      float p2 = __builtin_amdgcn_exp2f(sA[j][2]);
      float p3 = __builtin_amdgcn_exp2f(sA[j][3]);
      u32x2 pk;
      pk.x = cvtpk(p0, p1);
      pk.y = cvtpk(p2, p3);
      *(u32x2*)(Ps + qrow0 * 72 + j * 16 + lk * 4) = pk;
    }
#pragma unroll
    for (int j = 0; j < 4; ++j) {
      float p0 = __builtin_amdgcn_exp2f(sB[j][0]);
      float p1 = __builtin_amdgcn_exp2f(sB[j][1]);
      float p2 = __builtin_amdgcn_exp2f(sB[j][2]);
      float p3 = __builtin_amdgcn_exp2f(sB[j][3]);
      u32x2 pk;
      pk.x = cvtpk(p0, p1);
      pk.y = cvtpk(p2, p3);
      *(u32x2*)(Ps + (64 + qrow0) * 72 + j * 16 + lk * 4) = pk;
    }

    // ---- O^T += V^T P ; l += 1^T P (Ps rows wave-private: no barrier) ----
    const unsigned short* vt = Vt[cur];
    __builtin_amdgcn_s_setprio(1);
#pragma unroll
    for (int kk = 0; kk < 2; ++kk) {
      bf16x8 pa0 = *(const bf16x8*)(Ps + qrow0 * 72 + kk * 32 + lk * 8);
      bf16x8 pa1 = *(const bf16x8*)(Ps + (64 + qrow0) * 72 + kk * 32 + lk * 8);
      olA = __builtin_amdgcn_mfma_f32_16x16x32_bf16(ones, pa0, olA, 0, 0, 0);
      olB = __builtin_amdgcn_mfma_f32_16x16x32_bf16(ones, pa1, olB, 0, 0, 0);
#pragma unroll
      for (int j = 0; j < 4; ++j) {
        const int d = j * 16 + lrow;
        bf16x8 vb = *(const bf16x8*)(vt + d * 64 + ((((kk * 4 + lk) ^ (d & 7)) & 7) << 3));
        oA[j] = __builtin_amdgcn_mfma_f32_16x16x32_bf16(vb, pa0, oA[j], 0, 0, 0);
        oB[j] = __builtin_amdgcn_mfma_f32_16x16x32_bf16(vb, pa1, oB[j], 0, 0, 0);
      }
    }
    __builtin_amdgcn_s_setprio(0);

    cur ^= 1;
    __syncthreads();
  }

  // ---- epilogue: write unnormalized O (bf16) + (l, m) per q-row ----
  const long base = ((long)sp * 64 + bh) * 2048;     // row base for this split
  const long qlA = base + qt * 128 + qrow0;
  const long qlB = qlA + 64;
#pragma unroll
  for (int j = 0; j < 4; ++j) {
    u32x2 pk;
    pk.x = cvtpk(oA[j][0], oA[j][1]);
    pk.y = cvtpk(oA[j][2], oA[j][3]);
    *(u32x2*)(Op + qlA * 64 + j * 16 + lk * 4) = pk;
    pk.x = cvtpk(oB[j][0], oB[j][1]);
    pk.y = cvtpk(oB[j][2], oB[j][3]);
    *(u32x2*)(Op + qlB * 64 + j * 16 + lk * 4) = pk;
  }
  if (lk == 0) {
    Lm[qlA] = make_float2(olA[0], mrA);
    Lm[qlB] = make_float2(olB[0], mrB);
  }
}

// ---------------- split-K combine: Y = (O0*w0 + O1*w1)/(l0*w0 + l1*w1) -----
__global__ __launch_bounds__(256) void attn_combine_kernel(
    const unsigned short* __restrict__ Op,
    const float2* __restrict__ Lm,
    unsigned short* __restrict__ Y)
{
  const int t = blockIdx.x * 256 + threadIdx.x;   // 1,048,576 threads
  const int d0 = t & 7;
  const int ql = (t >> 3) & 2047;
  const int bh = t >> 14;
  const long row = (long)bh * 2048 + ql;
  const float2 lm0 = Lm[row];
  const float2 lm1 = Lm[131072 + row];
  const float m = fmaxf(lm0.y, lm1.y);
  const float w0 = __builtin_amdgcn_exp2f(lm0.y - m);
  const float w1 = __builtin_amdgcn_exp2f(lm1.y - m);
  const float dn = 1.f / (lm0.x * w0 + lm1.x * w1);
  const float c0 = w0 * dn, c1 = w1 * dn;
  bf16x8 o0 = *(const bf16x8*)(Op + row * 64 + d0 * 8);
  bf16x8 o1 = *(const bf16x8*)(Op + (131072L + row) * 64 + d0 * 8);
  u32x4 pk;
  float v0, v1;
  v0 = bf2f((unsigned short)o0[0]) * c0 + bf2f((unsigned short)o1[0]) * c1;
  v1 = bf2f((unsigned short)o0[1]) * c0 + bf2f((unsigned short)o1[1]) * c1;
  pk.x = cvtpk(v0, v1);
  v0 = bf2f((unsigned short)o0[2]) * c0 + bf2f((unsigned short)o1[2]) * c1;
  v1 = bf2f((unsigned short)o0[3]) * c0 + bf2f((unsigned short)o1[3]) * c1;
  pk.y = cvtpk(v0, v1);
  v0 = bf2f((unsigned short)o0[4]) * c0 + bf2f((unsigned short)o1[4]) * c1;
  v1 = bf2f((unsigned short)o0[5]) * c0 + bf2f((unsigned short)o1[5]) * c1;
  pk.z = cvtpk(v0, v1);
  v0 = bf2f((unsigned short)o0[6]) * c0 + bf2f((unsigned short)o1[6]) * c1;
  v1 = bf2f((unsigned short)o0[7]) * c0 + bf2f((unsigned short)o1[7]) * c1;
  pk.w = cvtpk(v0, v1);
  const int b = bh >> 4, h = bh & 15;
  *(u32x4*)(Y + ((long)b * 2048 + ql) * 1024 + h * 64 + d0 * 8) = pk;
}

// ---------------- launcher ----------------
extern "C" void kernel_launch(void* const* d_in, const int* in_sizes, int n_in,
                              void* d_out, int out_size, void* d_ws, size_t ws_size,
                              hipStream_t stream) {
  (void)in_sizes; (void)n_in; (void)out_size; (void)ws_size;
  const float* x   = (const float*)d_in[0];
  const float* enc = (const float*)d_in[1];
  const float* Wq  = (const float*)d_in[2];
  const float* bq  = (const float*)d_in[3];
  const float* Wk  = (const float*)d_in[4];
  const float* bk  = (const float*)d_in[5];
  const float* Wv  = (const float*)d_in[6];
  const float* bv  = (const float*)d_in[7];
  const float* Wp  = (const float*)d_in[8];
  const float* bp  = (const float*)d_in[9];

  const long M = 4L * 2048;
  const long C = 1024;

  char* ws = (char*)d_ws;
  size_t off = 0;
  auto alloc = [&](size_t bytes) {
    char* p = ws + off;
    off += (bytes + 255) & ~(size_t)255;
    return p;
  };
  unsigned short* Wqb = (unsigned short*)alloc(C * C * 2);
  unsigned short* Wkb = (unsigned short*)alloc(C * C * 2);
  unsigned short* Wvb = (unsigned short*)alloc(C * C * 2);
  unsigned short* Wpb = (unsigned short*)alloc(C * C * 2);
  unsigned short* Qw  = (unsigned short*)alloc(M * C * 2);
  unsigned short* Kw  = (unsigned short*)alloc(M * C * 2);
  unsigned short* VTw = (unsigned short*)alloc(M * C * 2);  // V^T [1024][8192]
  unsigned short* Yb  = (unsigned short*)alloc(M * C * 2);
  unsigned short* Op  = (unsigned short*)alloc(2L * M * C * 2);  // split-K partials
  float2* Lm = (float2*)alloc(2L * 64 * 2048 * sizeof(float2));  // 2 MB

  {
    int w4 = (int)(C * C / 4);
    cvtw_kernel<<<dim3(1024, 4), 256, 0, stream>>>(
        (const float4*)Wq, (const float4*)Wk, (const float4*)Wv, (const float4*)Wp,
        (ushort4*)Wqb, (ushort4*)Wkb, (ushort4*)Wvb, (ushort4*)Wpb, w4);
  }

  // Q/K/V in one dispatch; fp32 inputs converted in the A-staging path.
  // Q scaled by (1/8)*log2(e); V written transposed.
  const float qscale = 0.125f * 1.44269504088896f;
  gemm_qkv_kernel<<<1536, 256, 0, stream>>>(
      x, enc, Wqb, Wkb, Wvb, bq, bk, bv, Qw, Kw, VTw, qscale);

  attn_kernel<<<2048, 256, 0, stream>>>(Qw, Kw, VTw, Op, Lm);
  attn_combine_kernel<<<4096, 256, 0, stream>>>(Op, Lm, Yb);

  gemm_p_kernel<<<512, 256, 0, stream>>>(Yb, Wpb, bp, (float*)d_out);
}

// Round 11
// 284.910 us; speedup vs baseline: 1.0848x; 1.0848x over previous
//
#include <hip/hip_runtime.h>

typedef short bf16x8 __attribute__((ext_vector_type(8)));
typedef float f32x4 __attribute__((ext_vector_type(4)));
typedef unsigned int u32x2 __attribute__((ext_vector_type(2)));
typedef unsigned int u32x4 __attribute__((ext_vector_type(4)));

#define AS1 __attribute__((address_space(1)))
#define AS3 __attribute__((address_space(3)))

__device__ __forceinline__ void gld16(void* lds, const void* g) {
  __builtin_amdgcn_global_load_lds((const AS1 unsigned int*)g,
                                   (AS3 unsigned int*)lds, 16, 0, 0);
}

__device__ __forceinline__ unsigned short f2bf(float f) {
  union { float f; unsigned int u; } c; c.f = f;
  return (unsigned short)((c.u + 0x7FFFu + ((c.u >> 16) & 1u)) >> 16);
}

// single-instruction RNE f32->bf16
__device__ __forceinline__ unsigned short cvt1(float x) {
  unsigned int r;
  asm("v_cvt_pk_bf16_f32 %0, %1, %1" : "=v"(r) : "v"(x));
  return (unsigned short)r;
}

// packed RNE f32x2 -> bf16x2 in one instr
__device__ __forceinline__ unsigned int cvtpk(float lo, float hi) {
  unsigned int r;
  asm("v_cvt_pk_bf16_f32 %0, %1, %2" : "=v"(r) : "v"(lo), "v"(hi));
  return r;
}

__device__ __forceinline__ float bf2f(unsigned short u) {
  union { unsigned int u; float f; } c; c.u = ((unsigned int)u) << 16;
  return c.f;
}

// nested-triple max -> clang fuses v_max3_f32
__device__ __forceinline__ float fmax3(float a, float b, float c) {
  return fmaxf(fmaxf(a, b), c);
}

// ---------------- fp32 -> bf16 conversion (x and enc fused via grid.y) ------
__global__ void cvt_kernel(const float4* __restrict__ in0,
                           const float4* __restrict__ in1,
                           ushort4* __restrict__ out0,
                           ushort4* __restrict__ out1, int n4) {
  const float4* in = blockIdx.y ? in1 : in0;
  ushort4* out = blockIdx.y ? out1 : out0;
  int i = blockIdx.x * blockDim.x + threadIdx.x;
  int stride = gridDim.x * blockDim.x;
  for (; i < n4; i += stride) {
    float4 v = in[i];
    ushort4 o;
    o.x = f2bf(v.x); o.y = f2bf(v.y); o.z = f2bf(v.z); o.w = f2bf(v.w);
    out[i] = o;
  }
}

// all four 1024x1024 weights in one dispatch (blockIdx.y selects)
__global__ void cvtw_kernel(const float4* w0, const float4* w1,
                            const float4* w2, const float4* w3,
                            ushort4* o0, ushort4* o1, ushort4* o2, ushort4* o3,
                            int n4) {
  const float4* in; ushort4* out;
  switch (blockIdx.y) {
    case 0: in = w0; out = o0; break;
    case 1: in = w1; out = o1; break;
    case 2: in = w2; out = o2; break;
    default: in = w3; out = o3; break;
  }
  int i = blockIdx.x * blockDim.x + threadIdx.x;
  int stride = gridDim.x * blockDim.x;
  for (; i < n4; i += stride) {
    float4 v = in[i];
    ushort4 o;
    o.x = f2bf(v.x); o.y = f2bf(v.y); o.z = f2bf(v.z); o.w = f2bf(v.w);
    out[i] = o;
  }
}

// ---------------- fused QKV projection GEMM --------------------------------
// 128x128 tile, BK=32, 256 threads (4 waves, 2x2). 1D grid 1536, XCD-swizzled.
__global__ __launch_bounds__(256) void gemm_qkv_kernel(
    const unsigned short* __restrict__ Xb,
    const unsigned short* __restrict__ Eb,
    const unsigned short* __restrict__ Wqb,
    const unsigned short* __restrict__ Wkb,
    const unsigned short* __restrict__ Wvb,
    const float* __restrict__ bq,
    const float* __restrict__ bk,
    const float* __restrict__ bv,
    unsigned short* __restrict__ Qw,
    unsigned short* __restrict__ Kw,
    unsigned short* __restrict__ VTw,
    float qscale)
{
  __shared__ alignas(16) unsigned short As[2][4 * 128 * 8];
  __shared__ alignas(16) unsigned short Bs[2][4 * 128 * 8];

  // bijective XCD swizzle: 1536 blocks, 192 per XCD
  const int bid = blockIdx.x;
  const int o = (bid & 7) * 192 + (bid >> 3);
  const int xx = o % 24;
  const int yy = o / 24;
  const int sec = xx >> 3;
  const int nx = xx & 7;

  const unsigned short* A = (sec == 0) ? Xb : Eb;
  const unsigned short* W = (sec == 0) ? Wqb : (sec == 1) ? Wkb : Wvb;
  const float* bias = (sec == 0) ? bq : (sec == 1) ? bk : bv;

  const int K = 1024, N = 1024;
  const int tid = threadIdx.x;
  const int lane = tid & 63;
  const int w = tid >> 6;
  const int wr = (w >> 1) * 64;
  const int wc = (w & 1) * 64;
  const int lrow = lane & 15;
  const int lk = lane >> 4;
  const long m0 = (long)yy * 128;
  const long n0 = (long)nx * 128;

  f32x4 acc[4][4] = {};

  const int c0 = tid, c1 = tid + 256;
  const unsigned short* Ag0 = A + (m0 + (c0 & 127)) * (long)K + (c0 >> 7) * 8;
  const unsigned short* Ag1 = A + (m0 + (c1 & 127)) * (long)K + (c1 >> 7) * 8;
  const unsigned short* Wg0 = W + (n0 + (c0 & 127)) * (long)K + (c0 >> 7) * 8;
  const unsigned short* Wg1 = W + (n0 + (c1 & 127)) * (long)K + (c1 >> 7) * 8;

  const int arow = wr + lrow;
  const int brow = wc + lrow;
  const int nt = K >> 5;

  gld16(As[0] + c0 * 8, Ag0);
  gld16(As[0] + c1 * 8, Ag1);
  gld16(Bs[0] + c0 * 8, Wg0);
  gld16(Bs[0] + c1 * 8, Wg1);

  int cur = 0;
  for (int t = 0; t < nt; ++t) {
    __syncthreads();
    if (t + 1 < nt) {
      const int kt = (t + 1) * 32;
      gld16(As[cur ^ 1] + c0 * 8, Ag0 + kt);
      gld16(As[cur ^ 1] + c1 * 8, Ag1 + kt);
      gld16(Bs[cur ^ 1] + c0 * 8, Wg0 + kt);
      gld16(Bs[cur ^ 1] + c1 * 8, Wg1 + kt);
    }
    const unsigned short* as = As[cur];
    const unsigned short* bs = Bs[cur];
    bf16x8 af[4], bfr[4];
#pragma unroll
    for (int i = 0; i < 4; ++i)
      af[i] = *(const bf16x8*)(as + (lk * 128 + arow + i * 16) * 8);
#pragma unroll
    for (int j = 0; j < 4; ++j)
      bfr[j] = *(const bf16x8*)(bs + (lk * 128 + brow + j * 16) * 8);
    if (sec != 2) {
#pragma unroll
      for (int i = 0; i < 4; ++i)
#pragma unroll
        for (int j = 0; j < 4; ++j)
          acc[i][j] = __builtin_amdgcn_mfma_f32_16x16x32_bf16(af[i], bfr[j], acc[i][j], 0, 0, 0);
    } else {
      // swapped: C[row = W-feature][col = t]
#pragma unroll
      for (int i = 0; i < 4; ++i)
#pragma unroll
        for (int j = 0; j < 4; ++j)
          acc[i][j] = __builtin_amdgcn_mfma_f32_16x16x32_bf16(bfr[i], af[j], acc[i][j], 0, 0, 0);
    }
    cur ^= 1;
  }

  if (sec != 2) {
    unsigned short* out = (sec == 0) ? Qw : Kw;
    const float scale = (sec == 0) ? qscale : 1.0f;
#pragma unroll
    for (int j = 0; j < 4; ++j) {
      const long col = n0 + wc + j * 16 + lrow;
      const float bv_ = bias[col];
#pragma unroll
      for (int i = 0; i < 4; ++i)
#pragma unroll
        for (int r = 0; r < 4; ++r) {
          const long row = m0 + wr + i * 16 + lk * 4 + r;
          out[row * (long)N + col] = cvt1((acc[i][j][r] + bv_) * scale);
        }
    }
  } else {
    // V^T: feat = n0 + wc + i*16 + lk*4 + r, t = m0 + wr + j*16 + lrow
#pragma unroll
    for (int i = 0; i < 4; ++i)
#pragma unroll
      for (int r = 0; r < 4; ++r) {
        const long feat = n0 + wc + i * 16 + lk * 4 + r;
        const float bv_ = bias[feat];
#pragma unroll
        for (int j = 0; j < 4; ++j) {
          const long col = m0 + wr + j * 16 + lrow;
          VTw[feat * 8192 + col] = cvt1(acc[i][j][r] + bv_);
        }
      }
  }
}

// ---------------- final projection GEMM (128x128, f32 out, XCD-swizzled) ---
__global__ __launch_bounds__(256) void gemm_p_kernel(
    const unsigned short* __restrict__ A,
    const unsigned short* __restrict__ W,
    const float* __restrict__ bias,
    float* __restrict__ outF)
{
  __shared__ alignas(16) unsigned short As[2][4 * 128 * 8];
  __shared__ alignas(16) unsigned short Bs[2][4 * 128 * 8];

  const int bid = blockIdx.x;
  const int o = (bid & 7) * 64 + (bid >> 3);
  const int nx = o & 7;
  const int yy = o >> 3;

  const int K = 1024, N = 1024;
  const int tid = threadIdx.x;
  const int lane = tid & 63;
  const int w = tid >> 6;
  const int wr = (w >> 1) * 64;
  const int wc = (w & 1) * 64;
  const int lrow = lane & 15;
  const int lk = lane >> 4;
  const long m0 = (long)yy * 128;
  const long n0 = (long)nx * 128;

  f32x4 acc[4][4] = {};

  const int c0 = tid, c1 = tid + 256;
  const unsigned short* Ag0 = A + (m0 + (c0 & 127)) * (long)K + (c0 >> 7) * 8;
  const unsigned short* Ag1 = A + (m0 + (c1 & 127)) * (long)K + (c1 >> 7) * 8;
  const unsigned short* Wg0 = W + (n0 + (c0 & 127)) * (long)K + (c0 >> 7) * 8;
  const unsigned short* Wg1 = W + (n0 + (c1 & 127)) * (long)K + (c1 >> 7) * 8;

  const int arow = wr + lrow;
  const int brow = wc + lrow;
  const int nt = K >> 5;

  gld16(As[0] + c0 * 8, Ag0);
  gld16(As[0] + c1 * 8, Ag1);
  gld16(Bs[0] + c0 * 8, Wg0);
  gld16(Bs[0] + c1 * 8, Wg1);

  int cur = 0;
  for (int t = 0; t < nt; ++t) {
    __syncthreads();
    if (t + 1 < nt) {
      const int kt = (t + 1) * 32;
      gld16(As[cur ^ 1] + c0 * 8, Ag0 + kt);
      gld16(As[cur ^ 1] + c1 * 8, Ag1 + kt);
      gld16(Bs[cur ^ 1] + c0 * 8, Wg0 + kt);
      gld16(Bs[cur ^ 1] + c1 * 8, Wg1 + kt);
    }
    const unsigned short* as = As[cur];
    const unsigned short* bs = Bs[cur];
    bf16x8 af[4], bfr[4];
#pragma unroll
    for (int i = 0; i < 4; ++i)
      af[i] = *(const bf16x8*)(as + (lk * 128 + arow + i * 16) * 8);
#pragma unroll
    for (int j = 0; j < 4; ++j)
      bfr[j] = *(const bf16x8*)(bs + (lk * 128 + brow + j * 16) * 8);
#pragma unroll
    for (int i = 0; i < 4; ++i)
#pragma unroll
      for (int j = 0; j < 4; ++j)
        acc[i][j] = __builtin_amdgcn_mfma_f32_16x16x32_bf16(af[i], bfr[j], acc[i][j], 0, 0, 0);
    cur ^= 1;
  }

#pragma unroll
  for (int j = 0; j < 4; ++j) {
    const long col = n0 + wc + j * 16 + lrow;
    const float bv_ = bias[col];
#pragma unroll
    for (int i = 0; i < 4; ++i)
#pragma unroll
      for (int r = 0; r < 4; ++r) {
        const long row = m0 + wr + i * 16 + lk * 4 + r;
        outF[row * (long)N + col] = acc[i][j][r] + bv_;
      }
  }
}

// ---------------- Flash attention (split-K, QBLK=128, V^T input) -----------
// R9-verified inner loop; each block handles half the K range (16 tiles).
// Epilogue writes unnormalized O (bf16) + (l, m) (f32); combine kernel merges.
__global__ __launch_bounds__(256) void attn_kernel(
    const unsigned short* __restrict__ Q,
    const unsigned short* __restrict__ K,
    const unsigned short* __restrict__ VT,
    unsigned short* __restrict__ Op,   // [sp][bh][ql][64] bf16 (unnormalized)
    float2* __restrict__ Lm)           // [sp][bh][ql] (l, m)
{
  __shared__ alignas(16) unsigned short Ks[2][8 * 64 * 8];  // [buf][dblk][t][8] linear
  __shared__ alignas(16) unsigned short Vt[2][64 * 64];     // [buf][d][t] chunk-swizzled
  __shared__ alignas(16) unsigned short Ps[128 * 72];       // [q][t] stride-72, wave-private rows

  const int tid = threadIdx.x;
  const int lane = tid & 63;
  const int w = tid >> 6;
  const int lrow = lane & 15;
  const int lk = lane >> 4;

  // XCD-aware decode: 2048 blocks; id = r8 + 8*(qt + 16*(sp + 2*s))
  const int id = blockIdx.x;
  const int r8 = id & 7;
  const int qt = (id >> 3) & 15;
  const int sp = (id >> 7) & 1;
  const int s = id >> 8;
  const int bh = r8 + 8 * s;
  const int h = bh & 15, b = bh >> 4;
  const long C = 1024, T = 2048, NQ = 2048;
  const int kt0 = sp * 1024;
  const int ktEnd = kt0 + 1024;

  const unsigned short* Qg = Q + ((long)b * NQ + qt * 128) * C + h * 64;
  const unsigned short* Kg0 = K + (long)b * T * C + h * 64;
  const unsigned short* Vg0 = VT + (long)(h * 64) * 8192 + b * 2048;

  {
    int c = tid;
    gld16(Ks[0] + c * 8, Kg0 + (long)(kt0 + (c & 63)) * C + (c >> 6) * 8);
    c = tid + 256;
    gld16(Ks[0] + c * 8, Kg0 + (long)(kt0 + (c & 63)) * C + (c >> 6) * 8);
    c = tid;
    gld16(Vt[0] + c * 8, Vg0 + (long)(c >> 3) * 8192 + kt0 + (((c & 7) ^ ((c >> 3) & 7)) * 8));
    c = tid + 256;
    gld16(Vt[0] + c * 8, Vg0 + (long)(c >> 3) * 8192 + kt0 + (((c & 7) ^ ((c >> 3) & 7)) * 8));
  }
  bf16x8 qf[2][2];
#pragma unroll
  for (int f = 0; f < 2; ++f)
#pragma unroll
    for (int kk = 0; kk < 2; ++kk)
      qf[f][kk] = *(const bf16x8*)(Qg + (long)(f * 64 + w * 16 + lrow) * C + (kk * 4 + lk) * 8);

  bf16x8 ones;
#pragma unroll
  for (int e = 0; e < 8; ++e) ones[e] = (short)0x3F80;

  __syncthreads();

  f32x4 oA[4] = {}, oB[4] = {};
  f32x4 olA = {}, olB = {};
  float mrA = 0.f, mrB = 0.f;
  int cur = 0;

  const int qrow0 = w * 16 + lrow;

  for (int kt = kt0; kt < ktEnd; kt += 64) {
    const bool more = (kt + 64 < ktEnd);
    if (more) {
      int c = tid;
      gld16(Ks[cur ^ 1] + c * 8, Kg0 + (long)(kt + 64 + (c & 63)) * C + (c >> 6) * 8);
      gld16(Vt[cur ^ 1] + c * 8,
            Vg0 + (long)(c >> 3) * 8192 + kt + 64 + (((c & 7) ^ ((c >> 3) & 7)) * 8));
      c = tid + 256;
      gld16(Ks[cur ^ 1] + c * 8, Kg0 + (long)(kt + 64 + (c & 63)) * C + (c >> 6) * 8);
      gld16(Vt[cur ^ 1] + c * 8,
            Vg0 + (long)(c >> 3) * 8192 + kt + 64 + (((c & 7) ^ ((c >> 3) & 7)) * 8));
    }

    // ---- S^T = K Q^T, preseeded with -mr ----
    f32x4 sA[4], sB[4];
#pragma unroll
    for (int j = 0; j < 4; ++j)
#pragma unroll
      for (int r = 0; r < 4; ++r) { sA[j][r] = -mrA; sB[j][r] = -mrB; }

    __builtin_amdgcn_s_setprio(1);
#pragma unroll
    for (int kk = 0; kk < 2; ++kk) {
#pragma unroll
      for (int j = 0; j < 4; ++j) {
        bf16x8 kf = *(const bf16x8*)(Ks[cur] + ((kk * 4 + lk) * 64 + j * 16 + lrow) * 8);
        sA[j] = __builtin_amdgcn_mfma_f32_16x16x32_bf16(kf, qf[0][kk], sA[j], 0, 0, 0);
        sB[j] = __builtin_amdgcn_mfma_f32_16x16x32_bf16(kf, qf[1][kk], sB[j], 0, 0, 0);
      }
    }
    __builtin_amdgcn_s_setprio(0);

    // ---- lane-local online softmax; s is already S - mr (max3-fused trees) ----
    float pmA, pmB;
    {
      float a0 = fmax3(sA[0][0], sA[0][1], sA[0][2]);
      float a1 = fmax3(sA[0][3], sA[1][0], sA[1][1]);
      float a2 = fmax3(sA[1][2], sA[1][3], sA[2][0]);
      float a3 = fmax3(sA[2][1], sA[2][2], sA[2][3]);
      float a4 = fmax3(sA[3][0], sA[3][1], sA[3][2]);
      pmA = fmax3(fmax3(a0, a1, a2), fmax3(a3, a4, sA[3][3]),
                  __shfl_xor(fmax3(a0, a1, a2), 16));
      // recompute-free form: reduce then shuffle
      float t = fmax3(fmax3(a0, a1, a2), a3, fmax3(a4, sA[3][3], sA[3][3]));
      t = fmaxf(t, __shfl_xor(t, 16));
      t = fmaxf(t, __shfl_xor(t, 32));
      pmA = t;
      float b0 = fmax3(sB[0][0], sB[0][1], sB[0][2]);
      float b1 = fmax3(sB[0][3], sB[1][0], sB[1][1]);
      float b2 = fmax3(sB[1][2], sB[1][3], sB[2][0]);
      float b3 = fmax3(sB[2][1], sB[2][2], sB[2][3]);
      float b4 = fmax3(sB[3][0], sB[3][1], sB[3][2]);
      float u = fmax3(fmax3(b0, b1, b2), b3, fmax3(b4, sB[3][3], sB[3][3]));
      u = fmaxf(u, __shfl_xor(u, 16));
      u = fmaxf(u, __shfl_xor(u, 32));
      pmB = u;
    }
    if (__any(fmaxf(pmA, pmB) > 8.0f)) {
      const float dmA = fmaxf(pmA, 0.f);
      const float alA = __builtin_amdgcn_exp2f(-dmA);
      mrA += dmA; olA *= alA;
      const float dmB = fmaxf(pmB, 0.f);
      const float alB = __builtin_amdgcn_exp2f(-dmB);
      mrB += dmB; olB *= alB;
#pragma unroll
      for (int j = 0; j < 4; ++j) {
        oA[j] *= alA;
        oB[j] *= alB;
#pragma unroll
        for (int r = 0; r < 4; ++r) { sA[j][r] -= dmA; sB[j][r] -= dmB; }
      }
    }
#pragma unroll
    for (int j = 0; j < 4; ++j) {
      float p0 = __builtin_amdgcn_exp2f(sA[j][0]);
      float p1 = __builtin_amdgcn_exp2f(sA[j][1]);
      float p2 = __builtin_amdgcn_exp2f(sA[j][2]);
      float p3 = __builtin_amdgcn_exp2f(sA[j][3]);
      u32x2 pk;
      pk.x = cvtpk(p0, p1);
      pk.y = cvtpk(p2, p3);
      *(u32x2*)(Ps + qrow0 * 72 + j * 16 + lk * 4) = pk;
    }
#pragma unroll
    for (int j = 0; j < 4; ++j) {
      float p0 = __builtin_amdgcn_exp2f(sB[j][0]);
      float p1 = __builtin_amdgcn_exp2f(sB[j][1]);
      float p2 = __builtin_amdgcn_exp2f(sB[j][2]);
      float p3 = __builtin_amdgcn_exp2f(sB[j][3]);
      u32x2 pk;
      pk.x = cvtpk(p0, p1);
      pk.y = cvtpk(p2, p3);
      *(u32x2*)(Ps + (64 + qrow0) * 72 + j * 16 + lk * 4) = pk;
    }

    // ---- O^T += V^T P ; l += 1^T P (Ps rows wave-private: no barrier) ----
    const unsigned short* vt = Vt[cur];
    __builtin_amdgcn_s_setprio(1);
#pragma unroll
    for (int kk = 0; kk < 2; ++kk) {
      bf16x8 pa0 = *(const bf16x8*)(Ps + qrow0 * 72 + kk * 32 + lk * 8);
      bf16x8 pa1 = *(const bf16x8*)(Ps + (64 + qrow0) * 72 + kk * 32 + lk * 8);
      olA = __builtin_amdgcn_mfma_f32_16x16x32_bf16(ones, pa0, olA, 0, 0, 0);
      olB = __builtin_amdgcn_mfma_f32_16x16x32_bf16(ones, pa1, olB, 0, 0, 0);
#pragma unroll
      for (int j = 0; j < 4; ++j) {
        const int d = j * 16 + lrow;
        bf16x8 vb = *(const bf16x8*)(vt + d * 64 + ((((kk * 4 + lk) ^ (d & 7)) & 7) << 3));
        oA[j] = __builtin_amdgcn_mfma_f32_16x16x32_bf16(vb, pa0, oA[j], 0, 0, 0);
        oB[j] = __builtin_amdgcn_mfma_f32_16x16x32_bf16(vb, pa1, oB[j], 0, 0, 0);
      }
    }
    __builtin_amdgcn_s_setprio(0);

    cur ^= 1;
    __syncthreads();
  }

  // ---- epilogue: write unnormalized O (bf16) + (l, m) per q-row ----
  const long base = ((long)sp * 64 + bh) * 2048;     // row base for this split
  const long qlA = base + qt * 128 + qrow0;
  const long qlB = qlA + 64;
#pragma unroll
  for (int j = 0; j < 4; ++j) {
    u32x2 pk;
    pk.x = cvtpk(oA[j][0], oA[j][1]);
    pk.y = cvtpk(oA[j][2], oA[j][3]);
    *(u32x2*)(Op + qlA * 64 + j * 16 + lk * 4) = pk;
    pk.x = cvtpk(oB[j][0], oB[j][1]);
    pk.y = cvtpk(oB[j][2], oB[j][3]);
    *(u32x2*)(Op + qlB * 64 + j * 16 + lk * 4) = pk;
  }
  if (lk == 0) {
    Lm[qlA] = make_float2(olA[0], mrA);
    Lm[qlB] = make_float2(olB[0], mrB);
  }
}

// ---------------- split-K combine: Y = (O0*w0 + O1*w1)/(l0*w0 + l1*w1) -----
__global__ __launch_bounds__(256) void attn_combine_kernel(
    const unsigned short* __restrict__ Op,
    const float2* __restrict__ Lm,
    unsigned short* __restrict__ Y)
{
  const int t = blockIdx.x * 256 + threadIdx.x;   // 1,048,576 threads
  const int d0 = t & 7;
  const int ql = (t >> 3) & 2047;
  const int bh = t >> 14;
  const long row = (long)bh * 2048 + ql;
  const float2 lm0 = Lm[row];
  const float2 lm1 = Lm[131072 + row];
  const float m = fmaxf(lm0.y, lm1.y);
  const float w0 = __builtin_amdgcn_exp2f(lm0.y - m);
  const float w1 = __builtin_amdgcn_exp2f(lm1.y - m);
  const float dn = 1.f / (lm0.x * w0 + lm1.x * w1);
  const float c0 = w0 * dn, c1 = w1 * dn;
  bf16x8 o0 = *(const bf16x8*)(Op + row * 64 + d0 * 8);
  bf16x8 o1 = *(const bf16x8*)(Op + (131072L + row) * 64 + d0 * 8);
  u32x4 pk;
  float v0, v1;
  v0 = bf2f((unsigned short)o0[0]) * c0 + bf2f((unsigned short)o1[0]) * c1;
  v1 = bf2f((unsigned short)o0[1]) * c0 + bf2f((unsigned short)o1[1]) * c1;
  pk.x = cvtpk(v0, v1);
  v0 = bf2f((unsigned short)o0[2]) * c0 + bf2f((unsigned short)o1[2]) * c1;
  v1 = bf2f((unsigned short)o0[3]) * c0 + bf2f((unsigned short)o1[3]) * c1;
  pk.y = cvtpk(v0, v1);
  v0 = bf2f((unsigned short)o0[4]) * c0 + bf2f((unsigned short)o1[4]) * c1;
  v1 = bf2f((unsigned short)o0[5]) * c0 + bf2f((unsigned short)o1[5]) * c1;
  pk.z = cvtpk(v0, v1);
  v0 = bf2f((unsigned short)o0[6]) * c0 + bf2f((unsigned short)o1[6]) * c1;
  v1 = bf2f((unsigned short)o0[7]) * c0 + bf2f((unsigned short)o1[7]) * c1;
  pk.w = cvtpk(v0, v1);
  const int b = bh >> 4, h = bh & 15;
  *(u32x4*)(Y + ((long)b * 2048 + ql) * 1024 + h * 64 + d0 * 8) = pk;
}

// ---------------- launcher ----------------
extern "C" void kernel_launch(void* const* d_in, const int* in_sizes, int n_in,
                              void* d_out, int out_size, void* d_ws, size_t ws_size,
                              hipStream_t stream) {
  (void)in_sizes; (void)n_in; (void)out_size; (void)ws_size;
  const float* x   = (const float*)d_in[0];
  const float* enc = (const float*)d_in[1];
  const float* Wq  = (const float*)d_in[2];
  const float* bq  = (const float*)d_in[3];
  const float* Wk  = (const float*)d_in[4];
  const float* bk  = (const float*)d_in[5];
  const float* Wv  = (const float*)d_in[6];
  const float* bv  = (const float*)d_in[7];
  const float* Wp  = (const float*)d_in[8];
  const float* bp  = (const float*)d_in[9];

  const long M = 4L * 2048;
  const long C = 1024;

  char* ws = (char*)d_ws;
  size_t off = 0;
  auto alloc = [&](size_t bytes) {
    char* p = ws + off;
    off += (bytes + 255) & ~(size_t)255;
    return p;
  };
  unsigned short* Xb  = (unsigned short*)alloc(M * C * 2);
  unsigned short* Eb  = (unsigned short*)alloc(M * C * 2);
  unsigned short* Wqb = (unsigned short*)alloc(C * C * 2);
  unsigned short* Wkb = (unsigned short*)alloc(C * C * 2);
  unsigned short* Wvb = (unsigned short*)alloc(C * C * 2);
  unsigned short* Wpb = (unsigned short*)alloc(C * C * 2);
  unsigned short* Qw  = (unsigned short*)alloc(M * C * 2);
  unsigned short* Kw  = (unsigned short*)alloc(M * C * 2);
  unsigned short* VTw = (unsigned short*)alloc(M * C * 2);  // V^T [1024][8192]
  unsigned short* Yb  = (unsigned short*)alloc(M * C * 2);
  float2* Lm = (float2*)alloc(2L * 64 * 2048 * sizeof(float2));  // 2 MB

  // Op (split-K partials, 2 x 16.78 MB bf16) aliases Xb+Eb — both dead
  // after gemm_qkv completes, and attn runs strictly after it on `stream`.
  unsigned short* Op = Xb;

  {
    int n4 = (int)(M * C / 4);
    int blocks = (n4 + 255) / 256; if (blocks > 2048) blocks = 2048;
    cvt_kernel<<<dim3(blocks, 2), 256, 0, stream>>>(
        (const float4*)x, (const float4*)enc, (ushort4*)Xb, (ushort4*)Eb, n4);
    int w4 = (int)(C * C / 4);
    cvtw_kernel<<<dim3(1024, 4), 256, 0, stream>>>(
        (const float4*)Wq, (const float4*)Wk, (const float4*)Wv, (const float4*)Wp,
        (ushort4*)Wqb, (ushort4*)Wkb, (ushort4*)Wvb, (ushort4*)Wpb, w4);
  }

  // Q/K/V in one dispatch; Q scaled by (1/8)*log2(e); V written transposed
  const float qscale = 0.125f * 1.44269504088896f;
  gemm_qkv_kernel<<<1536, 256, 0, stream>>>(
      Xb, Eb, Wqb, Wkb, Wvb, bq, bk, bv, Qw, Kw, VTw, qscale);

  attn_kernel<<<2048, 256, 0, stream>>>(Qw, Kw, VTw, Op, Lm);
  attn_combine_kernel<<<4096, 256, 0, stream>>>(Op, Lm, Yb);

  gemm_p_kernel<<<512, 256, 0, stream>>>(Yb, Wpb, bp, (float*)d_out);
}